// Round 3
// baseline (376.253 us; speedup 1.0000x reference)
//
#include <hip/hip_runtime.h>

#define M_VERT 32768
#define NBATCH 8
#define FIN 32
#define RANK 5
#define FILT 32
#define E_NNZ 262144
#define ROWLEN 256                    // NBATCH*FIN elements per vertex row
#define EPAD (E_NNZ + 7 * M_VERT)     // upper bound on 8-padded edge count

typedef short short8 __attribute__((ext_vector_type(8)));
typedef float f32x4 __attribute__((ext_vector_type(4)));

__device__ __forceinline__ float bfl(unsigned int u) {           // low bf16 -> f32
    unsigned int x = u << 16; return __builtin_bit_cast(float, x);
}
__device__ __forceinline__ float bfh(unsigned int u) {           // high bf16 -> f32
    unsigned int x = u & 0xffff0000u; return __builtin_bit_cast(float, x);
}
__device__ __forceinline__ unsigned int f2bf(float f) {          // f32 -> bf16 (RNE)
    unsigned int x = __builtin_bit_cast(unsigned int, f);
    return (x + 0x7fffu + ((x >> 16) & 1u)) >> 16;
}
__device__ __forceinline__ unsigned int pk(float a, float b) {
    return f2bf(a) | (f2bf(b) << 16);
}

// ---------------- pack x -> T0 bf16, fused with hist (edge count) + packw ----------------
// pack: [N,M,Fin] fp32 -> T0 [M, n*32+fin] bf16 (M*32 threads, 8 elems each)
// hist: first E_NNZ threads also count edges per row (cnt must be pre-zeroed)
// packw: first 640 threads also pack W into MFMA B-fragment layout:
//   Wb[((k*2+ft)*64 + lane)*8 + j] = bf16(W[(fin*5+k)*32 + ft*16 + (lane&15)]), fin=(lane>>4)*8+j

__global__ void pack_kernel(const float* __restrict__ x, unsigned short* __restrict__ T0,
                            const int* __restrict__ rows, int* __restrict__ cnt,
                            const float* __restrict__ W, unsigned short* __restrict__ Wb) {
    int tid = blockIdx.x * blockDim.x + threadIdx.x;   // M*32 threads
    int m = tid >> 5;
    int r = tid & 31;
    int n = r >> 2;
    int q = r & 3;
    const float* src = x + ((size_t)n * M_VERT + m) * FIN + q * 8;
    float4 v0 = *(const float4*)(src);
    float4 v1 = *(const float4*)(src + 4);
    uint4 u;
    u.x = pk(v0.x, v0.y); u.y = pk(v0.z, v0.w);
    u.z = pk(v1.x, v1.y); u.w = pk(v1.z, v1.w);
    *(uint4*)(T0 + (size_t)m * ROWLEN + n * FIN + q * 8) = u;

    if (tid < E_NNZ) atomicAdd(&cnt[rows[tid]], 1);

    if (tid < 640) {
        int lane = tid & 63;
        int kf = tid >> 6;
        int k = kf >> 1, ft = kf & 1;
        int f = ft * 16 + (lane & 15);
        int fin0 = (lane >> 4) * 8;
        unsigned short tmp[8];
#pragma unroll
        for (int j = 0; j < 8; ++j)
            tmp[j] = (unsigned short)f2bf(W[((fin0 + j) * RANK + k) * FILT + f]);
        uint4 uw;
        uw.x = (unsigned int)tmp[0] | ((unsigned int)tmp[1] << 16);
        uw.y = (unsigned int)tmp[2] | ((unsigned int)tmp[3] << 16);
        uw.z = (unsigned int)tmp[4] | ((unsigned int)tmp[5] << 16);
        uw.w = (unsigned int)tmp[6] | ((unsigned int)tmp[7] << 16);
        *(uint4*)(Wb + (size_t)tid * 8) = uw;
    }
}

// ---------------- CSR build ----------------
// exclusive prefix sum of ceil8(cnt) -> rp[0..M]; re-zeroes fill cursor.
// Pad slots (up to next multiple of 8) are zeroed in ev (col 0, val 0.0), so the
// spmm loop needs no per-edge predication.
__global__ __launch_bounds__(1024) void scan_kernel(const int* __restrict__ cnt,
                                                    int* __restrict__ rp,
                                                    int* __restrict__ fill) {
    __shared__ int sums[1024];
    int t = threadIdx.x;
    int base = t * 32;
    int local[32];
    int s = 0;
#pragma unroll
    for (int i = 0; i < 32; ++i) {
        int c = (cnt[base + i] + 7) & ~7;        // pad to multiple of 8
        local[i] = c; s += c;
    }
    sums[t] = s;
    __syncthreads();
    for (int off = 1; off < 1024; off <<= 1) {
        int add = (t >= off) ? sums[t - off] : 0;
        __syncthreads();
        sums[t] += add;
        __syncthreads();
    }
    int pre = (t == 0) ? 0 : sums[t - 1];
#pragma unroll
    for (int i = 0; i < 32; ++i) { rp[base + i] = pre; pre += local[i]; }
    if (t == 1023) rp[M_VERT] = pre;
#pragma unroll
    for (int i = 0; i < 32; ++i) fill[base + i] = 0;
}

__global__ void scatter_kernel(const int* __restrict__ rows, const int* __restrict__ cols,
                               const float* __restrict__ vals, const int* __restrict__ rp,
                               int* __restrict__ fill, int2* __restrict__ ev) {
    int e = blockIdx.x * blockDim.x + threadIdx.x;
    if (e < E_NNZ) {
        int r = rows[e];
        int pos = rp[r] + atomicAdd(&fill[r], 1);
        int2 p; p.x = cols[e]; p.y = __builtin_bit_cast(int, vals[e]);
        ev[pos] = p;
    }
}

// ---------------- SpMM (bf16), batch-sliced + XCD-affine + nt-protected L2 ----------------
// Tout = L*Tin  or  2*L*Tin - Tsub, per batch-slice n (64 B of each row).
// blockIdx%8 == n pins each slice to one XCD; ev / Tsub / Tout accesses are
// NON-TEMPORAL so the XCD's 4 MiB L2 retains only the 2 MB Tin slice ->
// gather reuse (7/8 of demand) hits L2 instead of being evicted by the streams.
// Each 16-lane group owns ONE vertex and loops its OWN padded bound
// (divergent loop: exec-masked lanes issue no memory requests -> no waste
// traffic, unlike the round-2 wave-max loop). Pad slots are zero (ev memset).

__global__ __launch_bounds__(256) void spmm_kernel(const int* __restrict__ rp,
                                                   const unsigned long long* __restrict__ ev,
                                                   const unsigned short* __restrict__ Tin,
                                                   const unsigned short* __restrict__ Tsub,
                                                   unsigned short* __restrict__ Tout, int cheb) {
    int n  = blockIdx.x & 7;                     // batch slice -> XCD
    int vb = blockIdx.x >> 3;                    // vertex block 0..2047
    int lq = threadIdx.x & 15;                   // lane within 16-lane vertex group
    int m  = vb * 16 + (threadIdx.x >> 4);       // this group's vertex
    int s = rp[m];
    int e = rp[m + 1];                           // padded bound, uniform per group
    const char* tb = (const char*)Tin;
    unsigned int coff = ((unsigned int)n << 6) + ((unsigned int)lq << 2);
    float a0 = 0.f, a1 = 0.f;
    for (int j = s; j < e; j += 8) {
        unsigned long long ed[8];
#pragma unroll
        for (int i = 0; i < 8; ++i)
            ed[i] = __builtin_nontemporal_load(ev + j + i);   // {col, val} packed, nt
        unsigned int t[8];
#pragma unroll
        for (int i = 0; i < 8; ++i)
            t[i] = *(const unsigned int*)(tb + (((unsigned int)ed[i]) << 9) + coff);
#pragma unroll
        for (int i = 0; i < 8; ++i) {
            float v = __builtin_bit_cast(float, (unsigned int)(ed[i] >> 32));
            a0 += v * bfl(t[i]);
            a1 += v * bfh(t[i]);
        }
    }
    unsigned int moff = ((unsigned int)m << 9) + coff;
    if (cheb) {
        unsigned int o = __builtin_nontemporal_load(
            (const unsigned int*)((const char*)Tsub + moff));
        a0 = 2.f * a0 - bfl(o);
        a1 = 2.f * a1 - bfh(o);
    }
    __builtin_nontemporal_store(pk(a0, a1), (unsigned int*)((char*)Tout + moff));
}

// ---------------- final GEMM: out[n,m,f] = bias[f] + sum_k T_k[m, n*32+:] @ W_k ----------------
// MFMA 16x16x32 bf16; A straight from global (8 contiguous bf16/lane); n split
// across blocks for occupancy (grid = M/64 * 8).

__global__ __launch_bounds__(256) void gemm_kernel(const unsigned short* __restrict__ T0,
                                                   const unsigned short* __restrict__ T1,
                                                   const unsigned short* __restrict__ T2,
                                                   const unsigned short* __restrict__ T3,
                                                   const unsigned short* __restrict__ T4,
                                                   const unsigned short* __restrict__ Wb,
                                                   const float* __restrict__ bias,
                                                   float* __restrict__ out) {
    int w = threadIdx.x >> 6;
    int l = threadIdx.x & 63;
    int n  = blockIdx.x & 7;
    int mb = blockIdx.x >> 3;
    int m0 = (mb * 4 + w) * 16;
    int lrow = l & 15;           // A's m-offset AND C's column f
    int quad = l >> 4;

    short8 bfrag[5][2];
#pragma unroll
    for (int kf = 0; kf < 10; ++kf)
        bfrag[kf >> 1][kf & 1] = *(const short8*)(Wb + ((size_t)kf * 64 + l) * 8);

    float b0 = bias[lrow];
    float b1 = bias[16 + lrow];

    const unsigned short* Ts[5] = {T0, T1, T2, T3, T4};
    size_t abase = (size_t)(m0 + lrow) * ROWLEN + quad * 8 + n * FIN;

    f32x4 c0 = {0.f, 0.f, 0.f, 0.f};
    f32x4 c1 = {0.f, 0.f, 0.f, 0.f};
#pragma unroll
    for (int k = 0; k < 5; ++k) {
        short8 a = *(const short8*)(Ts[k] + abase);
        c0 = __builtin_amdgcn_mfma_f32_16x16x32_bf16(a, bfrag[k][0], c0, 0, 0, 0);
        c1 = __builtin_amdgcn_mfma_f32_16x16x32_bf16(a, bfrag[k][1], c1, 0, 0, 0);
    }
    float* op = out + ((size_t)n * M_VERT + m0) * FILT;
#pragma unroll
    for (int r = 0; r < 4; ++r) {
        int orow = quad * 4 + r;
        op[(size_t)orow * FILT + lrow]      = c0[r] + b0;
        op[(size_t)orow * FILT + 16 + lrow] = c1[r] + b1;
    }
}

// ---------------- launch ----------------

extern "C" void kernel_launch(void* const* d_in, const int* in_sizes, int n_in,
                              void* d_out, int out_size, void* d_ws, size_t ws_size,
                              hipStream_t stream) {
    const float* x    = (const float*)d_in[0];
    const float* vals = (const float*)d_in[1];
    const float* W    = (const float*)d_in[2];
    const float* bias = (const float*)d_in[3];
    const int*   rows = (const int*)d_in[4];
    const int*   cols = (const int*)d_in[5];
    float* out = (float*)d_out;

    // workspace: 5 bf16 T buffers (16 MiB each) + CSR (rp/fill/ev) + Wb
    const size_t TSZ = (size_t)M_VERT * ROWLEN;
    unsigned short* T0 = (unsigned short*)d_ws;
    unsigned short* T1 = T0 + TSZ;
    unsigned short* T2 = T1 + TSZ;
    unsigned short* T3 = T2 + TSZ;
    unsigned short* T4 = T3 + TSZ;
    int*  rp   = (int*)(T4 + TSZ);
    int*  fill = rp + (M_VERT + 2);
    int2* ev   = (int2*)(fill + M_VERT);
    unsigned short* Wb = (unsigned short*)(ev + EPAD);

    hipMemsetAsync(fill, 0, M_VERT * sizeof(int), stream);
    hipMemsetAsync(ev, 0, (size_t)EPAD * sizeof(int2), stream);   // pad edges: col 0, val 0.0
    pack_kernel<<<M_VERT * 32 / 256, 256, 0, stream>>>(x, T0, rows, fill, W, Wb);
    scan_kernel<<<1, 1024, 0, stream>>>(fill, rp, fill);
    scatter_kernel<<<E_NNZ / 256, 256, 0, stream>>>(rows, cols, vals, rp, fill, ev);

    // Chebyshev recurrence, all T_k kept (bf16); batch-sliced XCD-affine SpMM
    const unsigned long long* evq = (const unsigned long long*)ev;
    spmm_kernel<<<(M_VERT / 16) * 8, 256, 0, stream>>>(rp, evq, T0, T0, T1, 0);
    spmm_kernel<<<(M_VERT / 16) * 8, 256, 0, stream>>>(rp, evq, T1, T0, T2, 1);
    spmm_kernel<<<(M_VERT / 16) * 8, 256, 0, stream>>>(rp, evq, T2, T1, T3, 1);
    spmm_kernel<<<(M_VERT / 16) * 8, 256, 0, stream>>>(rp, evq, T3, T2, T4, 1);

    // single fused epilogue GEMM
    gemm_kernel<<<(M_VERT / 64) * 8, 256, 0, stream>>>(T0, T1, T2, T3, T4, Wb, bias, out);
}

// Round 4
// 263.366 us; speedup vs baseline: 1.4286x; 1.4286x over previous
//
#include <hip/hip_runtime.h>

#define M_VERT 32768
#define NBATCH 8
#define FIN 32
#define RANK 5
#define FILT 32
#define E_NNZ 262144
#define ROWLEN 256                    // NBATCH*FIN elements per vertex row
#define EPAD (E_NNZ + 15 * M_VERT)    // upper bound on 16-padded edge count

typedef short short8 __attribute__((ext_vector_type(8)));
typedef float f32x4 __attribute__((ext_vector_type(4)));

__device__ __forceinline__ float bfl(unsigned int u) {           // low bf16 -> f32
    unsigned int x = u << 16; return __builtin_bit_cast(float, x);
}
__device__ __forceinline__ float bfh(unsigned int u) {           // high bf16 -> f32
    unsigned int x = u & 0xffff0000u; return __builtin_bit_cast(float, x);
}
__device__ __forceinline__ unsigned int f2bf(float f) {          // f32 -> bf16 (RNE)
    unsigned int x = __builtin_bit_cast(unsigned int, f);
    return (x + 0x7fffu + ((x >> 16) & 1u)) >> 16;
}
__device__ __forceinline__ unsigned int pk(float a, float b) {
    return f2bf(a) | (f2bf(b) << 16);
}

// ---------------- pack x -> T0 bf16, fused with hist (edge count) + packw ----------------
// pack: [N,M,Fin] fp32 -> T0 [M, n*32+fin] bf16 (M*32 threads, 8 elems each)
// hist: first E_NNZ threads also count edges per row (cnt must be pre-zeroed)
// packw: first 640 threads also pack W into MFMA B-fragment layout:
//   Wb[((k*2+ft)*64 + lane)*8 + j] = bf16(W[(fin*5+k)*32 + ft*16 + (lane&15)]), fin=(lane>>4)*8+j

__global__ void pack_kernel(const float* __restrict__ x, unsigned short* __restrict__ T0,
                            const int* __restrict__ rows, int* __restrict__ cnt,
                            const float* __restrict__ W, unsigned short* __restrict__ Wb) {
    int tid = blockIdx.x * blockDim.x + threadIdx.x;   // M*32 threads
    int m = tid >> 5;
    int r = tid & 31;
    int n = r >> 2;
    int q = r & 3;
    const float* src = x + ((size_t)n * M_VERT + m) * FIN + q * 8;
    float4 v0 = *(const float4*)(src);
    float4 v1 = *(const float4*)(src + 4);
    uint4 u;
    u.x = pk(v0.x, v0.y); u.y = pk(v0.z, v0.w);
    u.z = pk(v1.x, v1.y); u.w = pk(v1.z, v1.w);
    *(uint4*)(T0 + (size_t)m * ROWLEN + n * FIN + q * 8) = u;

    if (tid < E_NNZ) atomicAdd(&cnt[rows[tid]], 1);

    if (tid < 640) {
        int lane = tid & 63;
        int kf = tid >> 6;
        int k = kf >> 1, ft = kf & 1;
        int f = ft * 16 + (lane & 15);
        int fin0 = (lane >> 4) * 8;
        unsigned short tmp[8];
#pragma unroll
        for (int j = 0; j < 8; ++j)
            tmp[j] = (unsigned short)f2bf(W[((fin0 + j) * RANK + k) * FILT + f]);
        uint4 uw;
        uw.x = (unsigned int)tmp[0] | ((unsigned int)tmp[1] << 16);
        uw.y = (unsigned int)tmp[2] | ((unsigned int)tmp[3] << 16);
        uw.z = (unsigned int)tmp[4] | ((unsigned int)tmp[5] << 16);
        uw.w = (unsigned int)tmp[6] | ((unsigned int)tmp[7] << 16);
        *(uint4*)(Wb + (size_t)tid * 8) = uw;
    }
}

// ---------------- CSR build ----------------
// exclusive prefix sum of ceil16(cnt) -> rp[0..M]; re-zeroes fill cursor.
// Pad slots (to next multiple of 16) are zeroed in ev (col 0, val 0.0): the
// spmm loop runs 16 edges/iter unconditionally, no per-edge predication; pad
// gathers land on vertex 0's row (hot line) and contribute exact 0.

__global__ __launch_bounds__(1024) void scan_kernel(const int* __restrict__ cnt,
                                                    int* __restrict__ rp,
                                                    int* __restrict__ fill) {
    __shared__ int sums[1024];
    int t = threadIdx.x;
    int base = t * 32;
    int local[32];
    int s = 0;
#pragma unroll
    for (int i = 0; i < 32; ++i) {
        int c = (cnt[base + i] + 15) & ~15;      // pad to multiple of 16
        local[i] = c; s += c;
    }
    sums[t] = s;
    __syncthreads();
    for (int off = 1; off < 1024; off <<= 1) {
        int add = (t >= off) ? sums[t - off] : 0;
        __syncthreads();
        sums[t] += add;
        __syncthreads();
    }
    int pre = (t == 0) ? 0 : sums[t - 1];
#pragma unroll
    for (int i = 0; i < 32; ++i) { rp[base + i] = pre; pre += local[i]; }
    if (t == 1023) rp[M_VERT] = pre;
#pragma unroll
    for (int i = 0; i < 32; ++i) fill[base + i] = 0;
}

__global__ void scatter_kernel(const int* __restrict__ rows, const int* __restrict__ cols,
                               const float* __restrict__ vals, const int* __restrict__ rp,
                               int* __restrict__ fill, int2* __restrict__ ev) {
    int e = blockIdx.x * blockDim.x + threadIdx.x;
    if (e < E_NNZ) {
        int r = rows[e];
        int pos = rp[r] + atomicAdd(&fill[r], 1);
        int2 p; p.x = cols[e]; p.y = __builtin_bit_cast(int, vals[e]);
        ev[pos] = p;
    }
}

// ---------------- SpMM (bf16): Tout = L*Tin  or  2*L*Tin - Tsub ----------------
// R0 structure: one wave per vertex; rp via readfirstlane -> scalar (SMEM) ev
// loads; all 64 lanes gather the SAME row -> one coalesced 512B transaction per
// edge. Rows padded to 16 -> 16 outstanding gathers per wave, trip count 1 for
// ~99.6% of rows (deep MLP). ev/Tin/Tout cached (Tout is next dispatch's gather
// target); only Tsub (pure stream, never re-read) is non-temporal.

__global__ __launch_bounds__(256) void spmm_kernel(const int* __restrict__ rp,
                                                   const unsigned long long* __restrict__ ev,
                                                   const unsigned short* __restrict__ Tin,
                                                   const unsigned short* __restrict__ Tsub,
                                                   unsigned short* __restrict__ Tout, int cheb) {
    int w = threadIdx.x >> 6;
    int l = threadIdx.x & 63;
    int m = blockIdx.x * 4 + w;
    unsigned int coff = (unsigned int)l * 8u;    // byte offset within 512B row
    int s = __builtin_amdgcn_readfirstlane(rp[m]);
    int e = __builtin_amdgcn_readfirstlane(rp[m + 1]);
    const char* tb = (const char*)Tin;
    float a0 = 0.f, a1 = 0.f, a2 = 0.f, a3 = 0.f;
    for (int j = s; j < e; j += 16) {
        unsigned long long ed[16];
#pragma unroll
        for (int i = 0; i < 16; ++i) ed[i] = ev[j + i];          // uniform -> s_load
        uint2 t[16];
#pragma unroll
        for (int i = 0; i < 16; ++i)
            t[i] = *(const uint2*)(tb + (((unsigned int)ed[i]) << 9) + coff);
#pragma unroll
        for (int i = 0; i < 16; ++i) {
            float v = __builtin_bit_cast(float, (unsigned int)(ed[i] >> 32));
            a0 += v * bfl(t[i].x); a1 += v * bfh(t[i].x);
            a2 += v * bfl(t[i].y); a3 += v * bfh(t[i].y);
        }
    }
    size_t moff = (size_t)m * 512 + coff;
    if (cheb) {
        unsigned long long o = __builtin_nontemporal_load(
            (const unsigned long long*)((const char*)Tsub + moff));
        unsigned int ox = (unsigned int)o, oy = (unsigned int)(o >> 32);
        a0 = 2.f * a0 - bfl(ox); a1 = 2.f * a1 - bfh(ox);
        a2 = 2.f * a2 - bfl(oy); a3 = 2.f * a3 - bfh(oy);
    }
    uint2 r;
    r.x = pk(a0, a1); r.y = pk(a2, a3);
    *(uint2*)((char*)Tout + moff) = r;
}

// ---------------- final GEMM: out[n,m,f] = bias[f] + sum_k T_k[m, n*32+:] @ W_k ----------------
// MFMA 16x16x32 bf16; A straight from global (8 contiguous bf16/lane); n split
// across blocks for occupancy (grid = M/64 * 8). out stores are non-temporal
// (never re-read).

__global__ __launch_bounds__(256) void gemm_kernel(const unsigned short* __restrict__ T0,
                                                   const unsigned short* __restrict__ T1,
                                                   const unsigned short* __restrict__ T2,
                                                   const unsigned short* __restrict__ T3,
                                                   const unsigned short* __restrict__ T4,
                                                   const unsigned short* __restrict__ Wb,
                                                   const float* __restrict__ bias,
                                                   float* __restrict__ out) {
    int w = threadIdx.x >> 6;
    int l = threadIdx.x & 63;
    int n  = blockIdx.x & 7;
    int mb = blockIdx.x >> 3;
    int m0 = (mb * 4 + w) * 16;
    int lrow = l & 15;           // A's m-offset AND C's column f
    int quad = l >> 4;

    short8 bfrag[5][2];
#pragma unroll
    for (int kf = 0; kf < 10; ++kf)
        bfrag[kf >> 1][kf & 1] = *(const short8*)(Wb + ((size_t)kf * 64 + l) * 8);

    float b0 = bias[lrow];
    float b1 = bias[16 + lrow];

    const unsigned short* Ts[5] = {T0, T1, T2, T3, T4};
    size_t abase = (size_t)(m0 + lrow) * ROWLEN + quad * 8 + n * FIN;

    f32x4 c0 = {0.f, 0.f, 0.f, 0.f};
    f32x4 c1 = {0.f, 0.f, 0.f, 0.f};
#pragma unroll
    for (int k = 0; k < 5; ++k) {
        short8 a = *(const short8*)(Ts[k] + abase);
        c0 = __builtin_amdgcn_mfma_f32_16x16x32_bf16(a, bfrag[k][0], c0, 0, 0, 0);
        c1 = __builtin_amdgcn_mfma_f32_16x16x32_bf16(a, bfrag[k][1], c1, 0, 0, 0);
    }
    float* op = out + ((size_t)n * M_VERT + m0) * FILT;
#pragma unroll
    for (int r = 0; r < 4; ++r) {
        int orow = quad * 4 + r;
        __builtin_nontemporal_store(c0[r] + b0, &op[(size_t)orow * FILT + lrow]);
        __builtin_nontemporal_store(c1[r] + b1, &op[(size_t)orow * FILT + 16 + lrow]);
    }
}

// ---------------- launch ----------------

extern "C" void kernel_launch(void* const* d_in, const int* in_sizes, int n_in,
                              void* d_out, int out_size, void* d_ws, size_t ws_size,
                              hipStream_t stream) {
    const float* x    = (const float*)d_in[0];
    const float* vals = (const float*)d_in[1];
    const float* W    = (const float*)d_in[2];
    const float* bias = (const float*)d_in[3];
    const int*   rows = (const int*)d_in[4];
    const int*   cols = (const int*)d_in[5];
    float* out = (float*)d_out;

    // workspace: 5 bf16 T buffers (16 MiB each) + CSR (rp/fill/ev16) + Wb
    const size_t TSZ = (size_t)M_VERT * ROWLEN;
    unsigned short* T0 = (unsigned short*)d_ws;
    unsigned short* T1 = T0 + TSZ;
    unsigned short* T2 = T1 + TSZ;
    unsigned short* T3 = T2 + TSZ;
    unsigned short* T4 = T3 + TSZ;
    int*  rp   = (int*)(T4 + TSZ);
    int*  fill = rp + (M_VERT + 2);
    int2* ev   = (int2*)(fill + M_VERT);
    unsigned short* Wb = (unsigned short*)(ev + EPAD);

    hipMemsetAsync(fill, 0, M_VERT * sizeof(int), stream);
    hipMemsetAsync(ev, 0, (size_t)EPAD * sizeof(int2), stream);   // pad edges: col 0, val 0.0
    pack_kernel<<<M_VERT * 32 / 256, 256, 0, stream>>>(x, T0, rows, fill, W, Wb);
    scan_kernel<<<1, 1024, 0, stream>>>(fill, rp, fill);
    scatter_kernel<<<E_NNZ / 256, 256, 0, stream>>>(rows, cols, vals, rp, fill, ev);

    // Chebyshev recurrence, all T_k kept (bf16)
    const unsigned long long* evq = (const unsigned long long*)ev;
    spmm_kernel<<<M_VERT / 4, 256, 0, stream>>>(rp, evq, T0, T0, T1, 0);
    spmm_kernel<<<M_VERT / 4, 256, 0, stream>>>(rp, evq, T1, T0, T2, 1);
    spmm_kernel<<<M_VERT / 4, 256, 0, stream>>>(rp, evq, T2, T1, T3, 1);
    spmm_kernel<<<M_VERT / 4, 256, 0, stream>>>(rp, evq, T3, T2, T4, 1);

    // single fused epilogue GEMM
    gemm_kernel<<<(M_VERT / 64) * 8, 256, 0, stream>>>(T0, T1, T2, T3, T4, Wb, bias, out);
}